// Round 3
// baseline (350.947 us; speedup 1.0000x reference)
//
#include <hip/hip_runtime.h>

typedef __bf16 bf16;
typedef __attribute__((ext_vector_type(8))) __bf16 bf16x8;
typedef __attribute__((ext_vector_type(4))) __bf16 bf16x4;
typedef __attribute__((ext_vector_type(2))) __bf16 bf16x2;
typedef __attribute__((ext_vector_type(4))) float f32x4;

#define MFMA16(a, b, c) __builtin_amdgcn_mfma_f32_16x16x32_bf16(a, b, c, 0, 0, 0)

constexpr int NH = 8, DD = 256, PP = 1024;

// ---- workspace byte offsets ----
constexpr size_t WB_TT  = 0;          // Tt  bf16 [64][1024][256]  ((M_h X + u 1^T)^T per n,h)
constexpr size_t WB_YT  = 33554432;   // Yt  bf16 [64][1024][256]  (Y^T per n,h)
constexpr size_t WB_XB  = 67108864;   // Xb  bf16 [8][256][1024]
constexpr size_t WB_XBT = 71303168;   // XbT bf16 [8][1024][256]
constexpr size_t WB_MB  = 75497472;   // Mb  bf16 [8][256][256]
constexpr size_t WB_UB  = 76546048;   // Ub  bf16 [256][2048]
constexpr size_t WB_U   = 77594624;   // u   f32  [8][256]
constexpr size_t WB_BP  = 77602816;   // bp  f32  [256]

// ---- flash LDS layout (bytes) ----
constexpr int FL_TT   = 0;      // Tt tile [64 q][256 i] bf16, 16B-block XOR swizzle
constexpr int FL_PT   = 32768;  // Pt tile [64 q][64 k] bf16, swizzled
constexpr int FL_RED  = 40960;  // red [64 q][4 w] f32 (tile-max partials)
constexpr int FL_RED2 = 41984;  // red2[64 q][4 w] f32 (row-sum partials)
constexpr int FL_SCL  = 43008;  // scl[64] f32
constexpr int FL_LRN  = 43264;  // lrun[64] f32
constexpr int FL_SZ   = 43520;

// ---------------- M_h (bf16) and U_h (bf16) precompute ----------------
// grid (4 i-tiles x 2 j-halves, 8 heads, 2 modes), 256 threads
__global__ __launch_bounds__(256, 1) void msa_mu(
    const float* __restrict__ Wk, const float* __restrict__ Wq,
    const float* __restrict__ Wo, const float* __restrict__ Wv,
    bf16* __restrict__ Mb, bf16* __restrict__ Ub) {
  __shared__ float lds[64 * 65];
  const int t = threadIdx.x;
  const int i0 = (blockIdx.x >> 1) * 64;
  const int jh = blockIdx.x & 1;
  const int h = blockIdx.y;
  const int mode = blockIdx.z;
  const int j0 = (t & 63) * 2 + jh * 128;
  const int ihalf = t >> 6;  // 0..3 -> rows ihalf*16..+15
  float acc0[16], acc1[16];
#pragma unroll
  for (int r = 0; r < 16; ++r) { acc0[r] = 0.f; acc1[r] = 0.f; }
  const float* __restrict__ W2 = (mode == 0) ? Wq : Wv;
  for (int dhc = 0; dhc < 256; dhc += 64) {
    __syncthreads();
    if (mode == 0) {
#pragma unroll
      for (int s = 0; s < 16; ++s) {
        int f = t + s * 256;
        int dh = f >> 6, ii = f & 63;
        lds[dh * 65 + ii] = Wk[(h * 256 + dhc + dh) * 256 + i0 + ii];
      }
    } else {
#pragma unroll
      for (int s = 0; s < 16; ++s) {
        int f = t + s * 256;
        int oo = f >> 6, dh = f & 63;
        lds[dh * 65 + oo] = Wo[(i0 + oo) * 2048 + h * 256 + dhc + dh];
      }
    }
    __syncthreads();
    for (int dl = 0; dl < 64; ++dl) {
      float2 wv = *reinterpret_cast<const float2*>(&W2[(h * 256 + dhc + dl) * 256 + j0]);
#pragma unroll
      for (int r = 0; r < 16; ++r) {
        float x = lds[dl * 65 + ihalf * 16 + r];
        acc0[r] = fmaf(x, wv.x, acc0[r]);
        acc1[r] = fmaf(x, wv.y, acc1[r]);
      }
    }
  }
  if (mode == 0) {
#pragma unroll
    for (int r = 0; r < 16; ++r) {
      int i = i0 + ihalf * 16 + r;
      bf16x2 v = { (__bf16)(acc0[r] * 0.0625f), (__bf16)(acc1[r] * 0.0625f) };
      *reinterpret_cast<bf16x2*>(&Mb[h * 65536 + i * 256 + j0]) = v;
    }
  } else {
#pragma unroll
    for (int r = 0; r < 16; ++r) {
      int o = i0 + ihalf * 16 + r;
      bf16x2 v = { (__bf16)acc0[r], (__bf16)acc1[r] };
      *reinterpret_cast<bf16x2*>(&Ub[o * 2048 + h * 256 + j0]) = v;
    }
  }
}

// ---------------- u_h = Wk_h^T bq_h / 16 ----------------
__global__ void msa_u(const float* __restrict__ Wk, const float* __restrict__ bq,
                      float* __restrict__ u) {
  __shared__ float bqs[256];
  const int h = blockIdx.x, t = threadIdx.x;
  bqs[t] = bq[h * 256 + t];
  __syncthreads();
  float acc = 0.f;
  for (int dh = 0; dh < 256; ++dh)
    acc = fmaf(Wk[(h * 256 + dh) * 256 + t], bqs[dh], acc);
  u[h * 256 + t] = acc * 0.0625f;
}

// ---------------- b' = bo + Wo bv ----------------
__global__ void msa_bp(const float* __restrict__ Wo, const float* __restrict__ bv,
                       const float* __restrict__ bo, float* __restrict__ bp) {
  const int o = blockIdx.x, t = threadIdx.x;
  float acc = 0.f;
  for (int f = t; f < 2048; f += 256)
    acc = fmaf(Wo[o * 2048 + f], bv[f], acc);
#pragma unroll
  for (int m = 32; m >= 1; m >>= 1) acc += __shfl_down(acc, m);
  __shared__ float part[4];
  if ((t & 63) == 0) part[t >> 6] = acc;
  __syncthreads();
  if (t == 0) bp[o] = bo[o] + part[0] + part[1] + part[2] + part[3];
}

// ---------------- X -> bf16 in both layouts ----------------
__global__ __launch_bounds__(256, 4) void msa_cvtX(
    const float* __restrict__ X, bf16* __restrict__ Xb, bf16* __restrict__ XbT) {
  __shared__ __bf16 tl[64 * 68];
  const int t = threadIdx.x;
  const int p0 = blockIdx.x * 64, d0 = blockIdx.y * 64, n = blockIdx.z;
  const float* __restrict__ Xn = X + (size_t)n * DD * PP;
#pragma unroll
  for (int rr = 0; rr < 4; ++rr) {
    int r = (t >> 4) + rr * 16, c = (t & 15) * 4;
    float4 v = *reinterpret_cast<const float4*>(Xn + (size_t)(d0 + r) * PP + p0 + c);
    bf16x4 pk = { (__bf16)v.x, (__bf16)v.y, (__bf16)v.z, (__bf16)v.w };
    *reinterpret_cast<bf16x4*>(Xb + (size_t)n * DD * PP + (size_t)(d0 + r) * PP + p0 + c) = pk;
    *reinterpret_cast<bf16x4*>(&tl[r * 68 + c]) = pk;
  }
  __syncthreads();
#pragma unroll
  for (int rr = 0; rr < 4; ++rr) {
    int pr = (t >> 4) + rr * 16, dc = (t & 15) * 4;
    bf16x4 pk = { tl[(dc + 0) * 68 + pr], tl[(dc + 1) * 68 + pr],
                  tl[(dc + 2) * 68 + pr], tl[(dc + 3) * 68 + pr] };
    *reinterpret_cast<bf16x4*>(XbT + (size_t)n * PP * DD + (size_t)(p0 + pr) * DD + d0 + dc) = pk;
  }
}

// ---------------- Tt[n,h][q][i] = (M_h @ X_n)^T + u_h^T, bf16 MFMA ----------------
// grid (8 qb, 2 ib, 64 nh), 256 threads
__global__ __launch_bounds__(256, 2) void msa_T(
    const bf16* __restrict__ XbT, const bf16* __restrict__ Mb,
    const float* __restrict__ u, bf16* __restrict__ Ttg) {
  const int t = threadIdx.x, lane = t & 63, w = t >> 6;
  const int g = lane >> 4, ln = lane & 15;
  const int qw2 = w >> 1, iw = w & 1;
  const int qb = blockIdx.x, ib2 = blockIdx.y, nh = blockIdx.z;
  const int n = nh >> 3, h = nh & 7;
  const bf16* __restrict__ Xq = XbT + (size_t)n * (PP * DD) + (size_t)(qb * 128 + qw2 * 64) * DD;
  const bf16* __restrict__ Mh = Mb + (size_t)h * (DD * DD) + (size_t)(ib2 * 128 + iw * 64) * DD;
  f32x4 acc[4][4];
#pragma unroll
  for (int a = 0; a < 4; ++a)
#pragma unroll
    for (int b = 0; b < 4; ++b) { f32x4 z = {0.f, 0.f, 0.f, 0.f}; acc[a][b] = z; }
#pragma unroll
  for (int s = 0; s < 8; ++s) {
    bf16x8 a[4], b[4];
#pragma unroll
    for (int mq = 0; mq < 4; ++mq)
      a[mq] = *reinterpret_cast<const bf16x8*>(Xq + (size_t)(mq * 16 + ln) * DD + s * 32 + g * 8);
#pragma unroll
    for (int ni = 0; ni < 4; ++ni)
      b[ni] = *reinterpret_cast<const bf16x8*>(Mh + (size_t)(ni * 16 + ln) * DD + s * 32 + g * 8);
#pragma unroll
    for (int mq = 0; mq < 4; ++mq)
#pragma unroll
      for (int ni = 0; ni < 4; ++ni) acc[mq][ni] = MFMA16(a[mq], b[ni], acc[mq][ni]);
  }
  float uv[4];
#pragma unroll
  for (int ni = 0; ni < 4; ++ni)
    uv[ni] = u[h * 256 + ib2 * 128 + iw * 64 + ni * 16 + ln];
  bf16* __restrict__ outp = Ttg + (size_t)nh * (PP * DD);
#pragma unroll
  for (int mq = 0; mq < 4; ++mq)
#pragma unroll
    for (int ni = 0; ni < 4; ++ni)
#pragma unroll
      for (int r = 0; r < 4; ++r)
        outp[(size_t)(qb * 128 + qw2 * 64 + mq * 16 + 4 * g + r) * DD +
             ib2 * 128 + iw * 64 + ni * 16 + ln] = (__bf16)(acc[mq][ni][r] + uv[ni]);
}

// ---------------- fused flash attention, bf16 MFMA ----------------
// grid (16 qt, 8 h, 8 n), 256 threads (4 waves), FL_SZ dynamic LDS
// Tt tile staged once (loop-invariant); S A-frags direct from L2 (no dup);
// 2 barriers/kt; softmax stats replicated in registers across waves.
__global__ __launch_bounds__(256, 2) void msa_flash(
    const bf16* __restrict__ XbT, const bf16* __restrict__ Xb,
    const bf16* __restrict__ Ttg, const float* __restrict__ pos,
    bf16* __restrict__ Yt) {
  extern __shared__ char smc[];
  const int t = threadIdx.x;
  const int lane = t & 63, w = t >> 6;
  const int g = lane >> 4, ln = lane & 15;
  const int qt = blockIdx.x, h = blockIdx.y, n = blockIdx.z;
  const int qg0 = qt * 64, nh = n * 8 + h;
  const bf16* __restrict__ XbTn = XbT + (size_t)n * (PP * DD);
  const bf16* __restrict__ Xbn  = Xb + (size_t)n * (DD * PP);
  const bf16* __restrict__ Tth  = Ttg + (size_t)nh * (PP * DD);
  const float* __restrict__ posh = pos + (size_t)h * (PP * PP);
  float* redp  = (float*)(smc + FL_RED);
  float* red2p = (float*)(smc + FL_RED2);
  float* sclp  = (float*)(smc + FL_SCL);
  float* lrnp  = (float*)(smc + FL_LRN);

  // stage Tt tile [64 q][256 i] once, 16B-block XOR swizzle
#pragma unroll
  for (int c = 0; c < 8; ++c) {
    int flat = t + c * 256;
    int row = flat >> 5, cb = flat & 31;
    uint4 v = *reinterpret_cast<const uint4*>(Tth + (size_t)(qg0 + row) * DD + cb * 8);
    *reinterpret_cast<uint4*>(smc + FL_TT + row * 512 + ((cb ^ (row & 7)) << 4)) = v;
  }

  float mrun[4], lrun[4];
#pragma unroll
  for (int i = 0; i < 4; ++i) { mrun[i] = -3.402823466e38f; lrun[i] = 0.f; }
  f32x4 yacc[4][4];
#pragma unroll
  for (int a = 0; a < 4; ++a)
#pragma unroll
    for (int b = 0; b < 4; ++b) { f32x4 z = {0.f, 0.f, 0.f, 0.f}; yacc[a][b] = z; }
  __syncthreads();

  for (int kt = 0; kt < 16; ++kt) {
    const int kg0 = kt * 64;
    // A-frags: X^T k-rows, direct from global (L2-hot, no cross-wave dup)
    const bf16* arow = XbTn + (size_t)(kg0 + w * 16 + ln) * DD;
    bf16x8 af[8];
#pragma unroll
    for (int s = 0; s < 8; ++s)
      af[s] = *reinterpret_cast<const bf16x8*>(arow + s * 32 + g * 8);
    // pos[k = kg0+w*16+4g+r][q = qg0+q4*16+ln]
    const float* prow = posh + (size_t)(kg0 + w * 16 + 4 * g) * PP + qg0 + ln;
    float posv[4][4];
#pragma unroll
    for (int r = 0; r < 4; ++r)
#pragma unroll
      for (int q4 = 0; q4 < 4; ++q4)
        posv[q4][r] = prow[(size_t)r * PP + q4 * 16];
    // S = (X^T)(M X + u 1^T): m=k(16, this wave), n=q(64)
    f32x4 sacc[4];
#pragma unroll
    for (int q4 = 0; q4 < 4; ++q4) { f32x4 z = {0.f, 0.f, 0.f, 0.f}; sacc[q4] = z; }
#pragma unroll
    for (int s = 0; s < 8; ++s) {
#pragma unroll
      for (int q4 = 0; q4 < 4; ++q4) {
        const int q_ = q4 * 16 + ln;
        bf16x8 bfg = *reinterpret_cast<const bf16x8*>(
            smc + FL_TT + q_ * 512 + (((4 * s + g) ^ (q_ & 7)) << 4));
        sacc[q4] = MFMA16(af[s], bfg, sacc[q4]);
      }
    }
    // + pos; per-wave partial max over this wave's 16 k
    float pm[4];
#pragma unroll
    for (int q4 = 0; q4 < 4; ++q4) {
      f32x4 v = sacc[q4];
#pragma unroll
      for (int r = 0; r < 4; ++r) v[r] += posv[q4][r];
      sacc[q4] = v;
      float m_ = fmaxf(fmaxf(v[0], v[1]), fmaxf(v[2], v[3]));
      m_ = fmaxf(m_, __shfl_xor(m_, 16));
      m_ = fmaxf(m_, __shfl_xor(m_, 32));
      pm[q4] = m_;
    }
    if (lane < 16) {
#pragma unroll
      for (int q4 = 0; q4 < 4; ++q4) redp[(q4 * 16 + ln) * 4 + w] = pm[q4];
    }
    __syncthreads();  // barrier 1: red visible
    // finalize max (replicated in every lane); running stats in regs
    float scl_[4], mn_[4];
#pragma unroll
    for (int q4 = 0; q4 < 4; ++q4) {
      f32x4 rv = *reinterpret_cast<const f32x4*>(redp + (q4 * 16 + ln) * 4);
      float mt = fmaxf(fmaxf(rv[0], rv[1]), fmaxf(rv[2], rv[3]));
      float mo = mrun[q4];
      float mn = fmaxf(mo, mt);
      scl_[q4] = __expf(mo - mn);
      mrun[q4] = mn;
      mn_[q4] = mn;
    }
    // P = exp(S-mn) -> Pt (swizzled); per-wave partial row-sums -> red2
    float ps[4];
#pragma unroll
    for (int q4 = 0; q4 < 4; ++q4) {
      bf16x4 pk;
      float s_ = 0.f;
#pragma unroll
      for (int r = 0; r < 4; ++r) {
        float e = __expf(sacc[q4][r] - mn_[q4]);
        s_ += e;
        pk[r] = (__bf16)e;
      }
      const int q_ = q4 * 16 + ln;
      *reinterpret_cast<bf16x4*>(smc + FL_PT + q_ * 128 +
          ((((2 * w) + (g >> 1)) ^ (q_ & 7)) << 4) + ((g & 1) << 3)) = pk;
      s_ += __shfl_xor(s_, 16);
      s_ += __shfl_xor(s_, 32);
      ps[q4] = s_;
    }
    if (lane < 16) {
#pragma unroll
      for (int q4 = 0; q4 < 4; ++q4) red2p[(q4 * 16 + ln) * 4 + w] = ps[q4];
      if (w == 0) {
#pragma unroll
        for (int q4 = 0; q4 < 4; ++q4) sclp[q4 * 16 + ln] = scl_[q4];
      }
    }
    __syncthreads();  // barrier 2: Pt, red2, scl visible
    // lrun update (replicated)
#pragma unroll
    for (int q4 = 0; q4 < 4; ++q4) {
      f32x4 sv = *reinterpret_cast<const f32x4*>(red2p + (q4 * 16 + ln) * 4);
      lrun[q4] = lrun[q4] * scl_[q4] + (sv[0] + sv[1] + sv[2] + sv[3]);
    }
    // PV: rescale + accumulate; wave owns d-range w*64
#pragma unroll
    for (int mq = 0; mq < 4; ++mq) {
      f32x4 sc = *reinterpret_cast<const f32x4*>(sclp + mq * 16 + 4 * g);
#pragma unroll
      for (int nd = 0; nd < 4; ++nd)
#pragma unroll
        for (int r = 0; r < 4; ++r) yacc[mq][nd][r] *= sc[r];
    }
#pragma unroll
    for (int ks = 0; ks < 2; ++ks) {
      bf16x8 pa[4], xv[4];
#pragma unroll
      for (int mq = 0; mq < 4; ++mq) {
        const int q_ = mq * 16 + ln;
        pa[mq] = *reinterpret_cast<const bf16x8*>(
            smc + FL_PT + q_ * 128 + (((4 * ks + g) ^ (q_ & 7)) << 4));
      }
#pragma unroll
      for (int nd = 0; nd < 4; ++nd)
        xv[nd] = *reinterpret_cast<const bf16x8*>(
            Xbn + (size_t)(w * 64 + nd * 16 + ln) * PP + kg0 + ks * 32 + g * 8);
#pragma unroll
      for (int mq = 0; mq < 4; ++mq)
#pragma unroll
        for (int nd = 0; nd < 4; ++nd)
          yacc[mq][nd] = MFMA16(pa[mq], xv[nd], yacc[mq][nd]);
    }
  }

  // epilogue
  if (t < 16) {
#pragma unroll
    for (int q4 = 0; q4 < 4; ++q4) lrnp[q4 * 16 + ln] = lrun[q4];
  }
  __syncthreads();
  bf16* __restrict__ Ytp = Yt + (size_t)nh * (PP * DD);
#pragma unroll
  for (int mq = 0; mq < 4; ++mq) {
    f32x4 lv = *reinterpret_cast<const f32x4*>(lrnp + mq * 16 + 4 * g);
    f32x4 inv;
#pragma unroll
    for (int r = 0; r < 4; ++r) inv[r] = 1.0f / lv[r];
#pragma unroll
    for (int nd = 0; nd < 4; ++nd)
#pragma unroll
      for (int r = 0; r < 4; ++r)
        Ytp[(size_t)(qg0 + mq * 16 + 4 * g + r) * DD + w * 64 + nd * 16 + ln] =
            (__bf16)(yacc[mq][nd][r] * inv[r]);
  }
}

// ---------------- out = Ub @ Y + b', bf16 MFMA ----------------
// grid (32 pt, 8 n), 256 threads; Yt read exactly once
__global__ __launch_bounds__(256, 2) void msa_final3(
    const bf16* __restrict__ Ub, const bf16* __restrict__ Yt,
    const float* __restrict__ bp, float* __restrict__ out) {
  const int t = threadIdx.x, lane = t & 63, w = t >> 6;
  const int g = lane >> 4, ln = lane & 15;
  const int pt = blockIdx.x, n = blockIdx.y;
  const bf16* __restrict__ Ytn = Yt + (size_t)n * 8 * (PP * DD);
  f32x4 acc[4][2];
#pragma unroll
  for (int a = 0; a < 4; ++a)
#pragma unroll
    for (int b = 0; b < 2; ++b) { f32x4 z = {0.f, 0.f, 0.f, 0.f}; acc[a][b] = z; }
#pragma unroll 4
  for (int js = 0; js < 64; ++js) {
    const int hh = js >> 3, dd = (js & 7) * 32;
    bf16x8 a[4], b[2];
#pragma unroll
    for (int mo = 0; mo < 4; ++mo)
      a[mo] = *reinterpret_cast<const bf16x8*>(
          Ub + (size_t)(w * 64 + mo * 16 + ln) * 2048 + js * 32 + g * 8);
#pragma unroll
    for (int np = 0; np < 2; ++np)
      b[np] = *reinterpret_cast<const bf16x8*>(
          Ytn + ((size_t)hh * PP + pt * 32 + np * 16 + ln) * DD + dd + g * 8);
#pragma unroll
    for (int mo = 0; mo < 4; ++mo)
#pragma unroll
      for (int np = 0; np < 2; ++np) acc[mo][np] = MFMA16(a[mo], b[np], acc[mo][np]);
  }
#pragma unroll
  for (int mo = 0; mo < 4; ++mo) {
    f32x4 bv = *reinterpret_cast<const f32x4*>(bp + w * 64 + mo * 16 + 4 * g);
#pragma unroll
    for (int np = 0; np < 2; ++np)
#pragma unroll
      for (int r = 0; r < 4; ++r) {
        const int o = w * 64 + mo * 16 + 4 * g + r;
        out[((size_t)n * DD + o) * PP + pt * 32 + np * 16 + ln] = acc[mo][np][r] + bv[r];
      }
  }
}

extern "C" void kernel_launch(void* const* d_in, const int* in_sizes, int n_in,
                              void* d_out, int out_size, void* d_ws, size_t ws_size,
                              hipStream_t stream) {
  const float* X   = (const float*)d_in[0];
  const float* pos = (const float*)d_in[1];
  const float* Wk  = (const float*)d_in[2];
  // d_in[3] = bk: q-only constant, cancels in softmax over k. Unused.
  const float* Wq  = (const float*)d_in[4];
  const float* bq  = (const float*)d_in[5];
  const float* Wv  = (const float*)d_in[6];
  const float* bv  = (const float*)d_in[7];
  const float* Wo  = (const float*)d_in[8];
  const float* bo  = (const float*)d_in[9];

  char* ws = (char*)d_ws;
  bf16* Tt  = (bf16*)(ws + WB_TT);
  bf16* Yt  = (bf16*)(ws + WB_YT);
  bf16* Xb  = (bf16*)(ws + WB_XB);
  bf16* XbT = (bf16*)(ws + WB_XBT);
  bf16* Mb  = (bf16*)(ws + WB_MB);
  bf16* Ub  = (bf16*)(ws + WB_UB);
  float* u  = (float*)(ws + WB_U);
  float* bp = (float*)(ws + WB_BP);
  float* out = (float*)d_out;

  hipFuncSetAttribute(reinterpret_cast<const void*>(msa_flash),
                      hipFuncAttributeMaxDynamicSharedMemorySize, FL_SZ);

  msa_cvtX<<<dim3(16, 4, 8), 256, 0, stream>>>(X, Xb, XbT);
  msa_mu<<<dim3(8, 8, 2), 256, 0, stream>>>(Wk, Wq, Wo, Wv, Mb, Ub);
  msa_u<<<8, 256, 0, stream>>>(Wk, bq, u);
  msa_bp<<<256, 256, 0, stream>>>(Wo, bv, bo, bp);
  msa_T<<<dim3(8, 2, 64), 256, 0, stream>>>(XbT, Mb, u, Tt);
  msa_flash<<<dim3(16, 8, 8), 256, FL_SZ, stream>>>(XbT, Xb, Tt, pos, Yt);
  msa_final3<<<dim3(32, 8), 256, 0, stream>>>(Ub, Yt, bp, out);
}